// Round 3
// baseline (351.693 us; speedup 1.0000x reference)
//
#include <hip/hip_runtime.h>
#include <hip/hip_bf16.h>

#define NB 8
#define CC 256
#define OO 768
#define LL 512
#define VV 25
#define PP 3
#define KMAIN 768
#define ZPITCH 776   // 768 + 8, rows 1552 B (16B-aligned)

typedef __attribute__((ext_vector_type(8))) short short8v;
typedef __attribute__((ext_vector_type(4))) float float4v;

__device__ inline short bf16bits(float a) {
    __hip_bfloat16 h = __float2bfloat16(a);
    return *reinterpret_cast<short*>(&h);
}
__device__ inline unsigned pack_bf16x2(float a, float b) {
    __hip_bfloat16 ha = __float2bfloat16(a);
    __hip_bfloat16 hb = __float2bfloat16(b);
    unsigned short ua = *reinterpret_cast<unsigned short*>(&ha);
    unsigned short ub = *reinterpret_cast<unsigned short*>(&hb);
    return (unsigned)ua | ((unsigned)ub << 16);
}

// ---------------------------------------------------------------------------
// Kernel A: causal 9-tap window sum along l (validated rounds 1-2).
// ---------------------------------------------------------------------------
__global__ __launch_bounds__(256) void wsum_kernel(const float* __restrict__ x,
                                                   float* __restrict__ xs) {
    const int CHUNKS = 8;
    int t = blockIdx.x * 256 + threadIdx.x;
    if (t >= NB * CC * VV * CHUNKS) return;
    int v = t % VV;
    int r = t / VV;
    int chunk = r % CHUNKS;
    int nc = r / CHUNKS;
    int l0 = chunk * (LL / CHUNKS);
    const float* xp = x  + (size_t)nc * (LL * VV) + v;
    float*       op = xs + (size_t)nc * (LL * VV) + v;

    float ring[8];
    float run = 0.f;
    #pragma unroll
    for (int k = 0; k < 8; ++k) {
        int j = l0 - 8 + k;
        float val = (j >= 0) ? xp[j * VV] : 0.f;
        ring[k] = val;
        run += val;
    }
    for (int base = l0; base < l0 + LL / CHUNKS; base += 8) {
        #pragma unroll
        for (int k = 0; k < 8; ++k) {
            int l = base + k;
            float val = xp[l * VV];
            float o = run + val;
            op[l * VV] = o;
            run = o - ring[k];
            ring[k] = val;
        }
    }
}

// ---------------------------------------------------------------------------
// W' permutation: Wp[c*768 + p*256 + ci] = bf16( W[(p*256+c)*256 + ci] )
// ---------------------------------------------------------------------------
__global__ __launch_bounds__(256) void wperm_kernel(const float* __restrict__ W,
                                                    __hip_bfloat16* __restrict__ Wp) {
    int idx = blockIdx.x * 256 + threadIdx.x;
    if (idx >= OO * CC) return;
    int c = idx / KMAIN;
    int k = idx - c * KMAIN;
    int p = k >> 8;
    int ci = k & 255;
    Wp[idx] = __float2bfloat16(W[((p << 8) + c) * 256 + ci]);
}

// ---------------------------------------------------------------------------
// Fused kernel: per (n,l): Z[p,ci,w] = sum_v xs[ci,v] A[p,v,w]   (MFMA, tiny)
// then out[c,w] = sum_{p,ci} W'[c,pci] Z[pci,w]  (one K=768 GEMM, pipelined)
// epilogue BN + relu + residual + relu. In-place on d_out (xs aliases out).
// ---------------------------------------------------------------------------
template <bool USE_WB>
__global__ __launch_bounds__(256, 3) void fused_z_kernel(
    const float* xs,                        // aliases out (NOT restrict)
    const float* __restrict__ x,            // residual
    const float* __restrict__ W,            // fp32 weights (fallback)
    const __hip_bfloat16* __restrict__ Wp,  // permuted bf16 weights (if USE_WB)
    const float* __restrict__ A,
    const float* __restrict__ gamma, const float* __restrict__ beta,
    const float* __restrict__ mean, const float* __restrict__ var,
    float* out)
{
    __shared__ __align__(16) __hip_bfloat16 ZT[32 * ZPITCH];  // [w][k^swz]
    __shared__ float scsh[512];

    const int bid = blockIdx.x;
    const int n = bid >> 9;
    const int l = bid & 511;
    const int tid = threadIdx.x;
    const int lane = tid & 63;
    const int wid = tid >> 6;
    const int lcol = lane & 15;
    const int grp = lane >> 4;
    const int lk = grp << 3;
    const size_t nbase = (size_t)n * (CC * LL * VV);

    {   // BN coefficients
        float sc = gamma[tid] * rsqrtf(var[tid] + 1e-5f);
        scsh[tid] = sc;
        scsh[256 + tid] = beta[tid] - mean[tid] * sc;
    }

    const int swzA = (lcol & 7) << 3;   // same for w=lcol and w=16+lcol

    // ---------------- Z phase ----------------
    short8v bz[PP][2];
    #pragma unroll
    for (int p = 0; p < PP; ++p) {
        #pragma unroll
        for (int nt = 0; nt < 2; ++nt) {
            int w = nt * 16 + lcol;
            short8v t;
            #pragma unroll
            for (int j = 0; j < 8; ++j) {
                int v = lk + j;
                float f = (v < VV && w < VV) ? A[(p * VV + v) * VV + w] : 0.f;
                t[j] = bf16bits(f);
            }
            bz[p][nt] = t;
        }
    }

    #pragma unroll
    for (int i = 0; i < 4; ++i) {
        int miz = (wid << 2) + i;
        int ci = (miz << 4) + lcol;
        const float* xp = xs + nbase + (size_t)ci * (LL * VV) + l * VV;
        short8v az;
        #pragma unroll
        for (int j = 0; j < 8; ++j) {
            int v = lk + j;
            float f = (v < VV) ? xp[v] : 0.f;
            az[j] = bf16bits(f);
        }
        #pragma unroll
        for (int p = 0; p < PP; ++p) {
            int k0 = (p << 8) + (miz << 4) + (grp << 2);
            #pragma unroll
            for (int nt = 0; nt < 2; ++nt) {
                float4v acc = {0.f, 0.f, 0.f, 0.f};
                acc = __builtin_amdgcn_mfma_f32_16x16x32_bf16(az, bz[p][nt], acc, 0, 0, 0);
                int base = (nt * 16 + lcol) * ZPITCH;
                *reinterpret_cast<unsigned*>(&ZT[base + ((k0) ^ swzA)])     = pack_bf16x2(acc[0], acc[1]);
                *reinterpret_cast<unsigned*>(&ZT[base + ((k0 + 2) ^ swzA)]) = pack_bf16x2(acc[2], acc[3]);
            }
        }
    }
    __syncthreads();

    // ---------------- main GEMM: out[c,w] = sum_k W'[c,k] Z[k,w] ----------------
    float4v acc[4][2];
    #pragma unroll
    for (int m = 0; m < 4; ++m) {
        acc[m][0] = (float4v){0.f, 0.f, 0.f, 0.f};
        acc[m][1] = (float4v){0.f, 0.f, 0.f, 0.f};
    }

    const int b0 = lcol * ZPITCH;
    const int b1 = (16 + lcol) * ZPITCH;

    const __hip_bfloat16* wpb[4];
    const float* wpf[4];
    #pragma unroll
    for (int m = 0; m < 4; ++m) {
        int c = (((wid << 2) + m) << 4) + lcol;
        wpb[m] = Wp + (size_t)c * KMAIN + lk;
        wpf[m] = W + (size_t)c * 256;
    }

#define LOAD_A(kk, dst) do {                                                  \
    if (USE_WB) {                                                             \
        _Pragma("unroll")                                                     \
        for (int m_ = 0; m_ < 4; ++m_)                                        \
            dst[m_] = *(const short8v*)(wpb[m_] + (kk) * 32);                 \
    } else {                                                                  \
        int p_ = (kk) >> 3;                                                   \
        int ci0_ = (((kk) & 7) << 5) + lk;                                    \
        _Pragma("unroll")                                                     \
        for (int m_ = 0; m_ < 4; ++m_) {                                      \
            const float* rp_ = wpf[m_] + (p_ << 16) + ci0_;                   \
            short8v t_;                                                       \
            _Pragma("unroll")                                                 \
            for (int j_ = 0; j_ < 8; ++j_) t_[j_] = bf16bits(rp_[j_]);        \
            dst[m_] = t_;                                                     \
        }                                                                     \
    }                                                                         \
} while (0)

#define LOAD_B(kk, dst) do {                                                  \
    int e_ = (((kk) * 32 + lk) ^ swzA);                                       \
    dst[0] = *(const short8v*)&ZT[b0 + e_];                                   \
    dst[1] = *(const short8v*)&ZT[b1 + e_];                                   \
} while (0)

#define MFMA8(af, bf) do {                                                    \
    _Pragma("unroll")                                                         \
    for (int m_ = 0; m_ < 4; ++m_) {                                          \
        acc[m_][0] = __builtin_amdgcn_mfma_f32_16x16x32_bf16(af[m_], bf[0], acc[m_][0], 0, 0, 0); \
        acc[m_][1] = __builtin_amdgcn_mfma_f32_16x16x32_bf16(af[m_], bf[1], acc[m_][1], 0, 0, 0); \
    }                                                                         \
} while (0)

    short8v af0[4], af1[4], bf0[2], bf1[2];
    LOAD_A(0, af0);
    LOAD_B(0, bf0);
    #pragma unroll 1
    for (int kk = 0; kk < 24; kk += 2) {
        LOAD_A(kk + 1, af1);
        LOAD_B(kk + 1, bf1);
        MFMA8(af0, bf0);
        int kn = (kk + 2 < 24) ? (kk + 2) : 23;   // last prefetch harmless
        LOAD_A(kn, af0);
        LOAD_B(kn, bf0);
        MFMA8(af1, bf1);
    }

    // ---------------- epilogue ----------------
    #pragma unroll
    for (int m = 0; m < 4; ++m) {
        int c0 = ((((wid << 2) + m) << 4)) + (grp << 2);
        #pragma unroll
        for (int nt = 0; nt < 2; ++nt) {
            int w = nt * 16 + lcol;
            if (w < VV) {
                #pragma unroll
                for (int r = 0; r < 4; ++r) {
                    int c = c0 + r;
                    float val = fmaf(acc[m][nt][r], scsh[c], scsh[256 + c]);
                    val = fmaxf(val, 0.f);
                    size_t ad = nbase + (size_t)c * (LL * VV) + l * VV + w;
                    val = fmaxf(val + x[ad], 0.f);
                    out[ad] = val;
                }
            }
        }
    }
#undef LOAD_A
#undef LOAD_B
#undef MFMA8
}

extern "C" void kernel_launch(void* const* d_in, const int* in_sizes, int n_in,
                              void* d_out, int out_size, void* d_ws, size_t ws_size,
                              hipStream_t stream) {
    const float* x  = (const float*)d_in[0];
    const float* W  = (const float*)d_in[1];
    const float* A  = (const float*)d_in[2];
    const float* gm = (const float*)d_in[3];
    const float* bt = (const float*)d_in[4];
    const float* mn = (const float*)d_in[5];
    const float* vr = (const float*)d_in[6];
    float* out = (float*)d_out;

    const int threadsA = NB * CC * VV * 8;
    wsum_kernel<<<dim3((threadsA + 255) / 256), dim3(256), 0, stream>>>(x, out);

    bool useWb = ws_size >= (size_t)(OO * CC * sizeof(__hip_bfloat16));
    __hip_bfloat16* Wp = (__hip_bfloat16*)d_ws;
    if (useWb) {
        wperm_kernel<<<dim3((OO * CC + 255) / 256), dim3(256), 0, stream>>>(W, Wp);
        fused_z_kernel<true><<<dim3(NB * LL), dim3(256), 0, stream>>>(
            out, x, W, Wp, A, gm, bt, mn, vr, out);
    } else {
        fused_z_kernel<false><<<dim3(NB * LL), dim3(256), 0, stream>>>(
            out, x, W, Wp, A, gm, bt, mn, vr, out);
    }
}

// Round 4
// 128.720 us; speedup vs baseline: 2.7322x; 2.7322x over previous
//
#include <hip/hip_runtime.h>
#include <hip/hip_bf16.h>

#define NB 8
#define CC 256
#define OO 768
#define LL 512
#define VV 25
#define PP 3
#define KM 768
#define NKC 24          // K-chunks of 32
#define LT 4            // l's per block

typedef __attribute__((ext_vector_type(8))) short short8v;
typedef __attribute__((ext_vector_type(4))) float float4v;
typedef __attribute__((ext_vector_type(4))) int int4v;

__device__ inline short bf16b(float a){ __hip_bfloat16 h = __float2bfloat16(a); return *(short*)&h; }
__device__ inline unsigned pk2(float a, float b){
    __hip_bfloat16 ha = __float2bfloat16(a), hb = __float2bfloat16(b);
    unsigned short ua = *(unsigned short*)&ha, ub = *(unsigned short*)&hb;
    return (unsigned)ua | ((unsigned)ub << 16);
}
__device__ inline void gload_lds16(const void* g, void* s) {
    __builtin_amdgcn_global_load_lds((const __attribute__((address_space(1))) unsigned*)g,
                                     (__attribute__((address_space(3))) unsigned*)(s), 16, 0, 0);
}

// ---------------------------------------------------------------------------
// W' permutation into d_ws (bf16): Wp[c][k] = W[(p*256+c)][ci]
// k-order: k = cib*192 + p*64 + ci6,  ci = cib*64 + ci6
// ---------------------------------------------------------------------------
__global__ __launch_bounds__(256) void wperm_kernel(const float* __restrict__ W,
                                                    __hip_bfloat16* __restrict__ Wp) {
    int idx = blockIdx.x * 256 + threadIdx.x;
    if (idx >= OO * CC) return;
    int c = idx / KM;
    int k = idx - c * KM;
    int cib = k / 192, r = k - cib * 192;
    int p = r >> 6, ci6 = r & 63;
    Wp[idx] = __float2bfloat16(W[(p * 256 + c) * 256 + cib * 64 + ci6]);
}

// ---------------------------------------------------------------------------
// Fused: window-sum + Z-gen + K=768 MFMA GEMM + BN/relu/residual.
// Block = (n, 4 l's). 512 threads / 8 waves. No aliasing (out pure write).
// ---------------------------------------------------------------------------
__global__ __launch_bounds__(512, 2) void fused_main_kernel(
    const float* __restrict__ x,            // original input (window src + residual)
    const __hip_bfloat16* __restrict__ Wp,  // permuted bf16 weights
    const float* __restrict__ A,
    const float* __restrict__ gamma, const float* __restrict__ beta,
    const float* __restrict__ mean, const float* __restrict__ var,
    float* __restrict__ out)
{
    __shared__ __hip_bfloat16 Wb[2][256 * 32];   // W'-chunk dbuf (32 KB)
    __shared__ __hip_bfloat16 Zb[128 * 32];      // Z^T[lw][klocal] (8 KB)
    __shared__ __hip_bfloat16 xsh[256 * 32];     // ws-x [ci6*4+l][v pad32] (16 KB)
    __shared__ __hip_bfloat16 a2t[3 * 32 * 32];  // A^T [p*32+w][v pad32] (6 KB)
    __shared__ float scsh[512];

    const int tid  = threadIdx.x;
    const int lane = tid & 63, wid = tid >> 6;
    const int lcol = lane & 15, grp = lane >> 4;
    const int bid = blockIdx.x;
    const int n  = bid >> 7;
    const int l0 = (bid & 127) * LT;
    const int wm = wid >> 1, wn = wid & 1;       // main-GEMM wave grid 4M x 2N
    const int l_z = wid >> 1, mt_z = wid & 1;    // zgen wave roles

    // W-stage per-thread source pieces (same for both 16B pieces)
    const int c_st  = tid >> 2;                  // 0..127
    const int kb_st = (tid & 3) ^ ((c_st >> 1) & 3);

    // ---- prologue: zero pads, BN coefs ----
    {
        int4v z = {0, 0, 0, 0};
        ((int4v*)xsh)[tid] = z;
        ((int4v*)xsh)[tid + 512] = z;
        if (tid < 384) ((int4v*)a2t)[tid] = z;
        int c = tid & 255;
        float sc = gamma[c] * rsqrtf(var[c] + 1e-5f);
        if (tid < 256) scsh[tid] = sc;
        else           scsh[tid] = beta[c] - mean[c] * sc;
    }
    __syncthreads();
    // A^T scatter: a2t[p*32 + w][v ^ swz]
    for (int idx = tid; idx < PP * VV * VV; idx += 512) {
        int p = idx / 625, r = idx - p * 625, v = r / 25, w = r - v * 25;
        int R = p * 32 + w;
        int e = (((v >> 3) ^ ((R >> 1) & 3)) << 3) | (v & 7);
        a2t[R * 32 + e] = __float2bfloat16(A[idx]);
    }

    auto stage_w = [&](int buf, int kc_) {
        #pragma unroll
        for (int it = 0; it < 2; ++it) {
            const __hip_bfloat16* s = Wp + (size_t)(c_st + it * 128) * KM + kc_ * 32 + kb_st * 8;
            gload_lds16((const void*)s, (void*)((char*)&Wb[buf][0] + it * 8192 + wid * 1024));
        }
    };
    auto stage_xs = [&](int cib) {
        for (int cc = tid; cc < 1600; cc += 512) {
            int ci6 = cc / 25, v = cc - ci6 * 25;
            const float* xp = x + ((size_t)(n * CC + cib * 64 + ci6) * LL) * VV + v;
            float rbuf[12];
            #pragma unroll
            for (int j = 0; j < 12; ++j) {
                int lj = l0 - 8 + j;
                rbuf[j] = (lj >= 0) ? xp[(size_t)lj * VV] : 0.f;
            }
            float wsv = 0.f;
            #pragma unroll
            for (int j = 0; j < 9; ++j) wsv += rbuf[j];
            #pragma unroll
            for (int i = 0; i < 4; ++i) {
                int R = ci6 * 4 + i;
                int e = (((v >> 3) ^ ((R >> 2) & 3)) << 3) | (v & 7);
                xsh[R * 32 + e] = __float2bfloat16(wsv);
                if (i < 3) wsv += rbuf[9 + i] - rbuf[i];
            }
        }
    };

    float4v acc[4][4];
    #pragma unroll
    for (int i = 0; i < 4; ++i)
        #pragma unroll
        for (int j = 0; j < 4; ++j) acc[i][j] = (float4v){0.f, 0.f, 0.f, 0.f};

    stage_w(0, 0);   // prime

    #pragma unroll 1
    for (int kc = 0; kc < NKC; ++kc) {
        if ((kc % 6) == 0) {
            stage_xs(kc / 6);
            asm volatile("s_waitcnt lgkmcnt(0)" ::: "memory");
            __builtin_amdgcn_sched_barrier(0);
            __builtin_amdgcn_s_barrier();
        }

        // ---- Z-gen for this chunk: 2 MFMAs/wave ----
        {
            int p = ((kc % 6) >> 1), h = kc & 1;
            int ci6 = h * 32 + mt_z * 16 + lcol;
            int R = ci6 * 4 + l_z;
            short8v az = *(const short8v*)&xsh[R * 32 + ((grp ^ ((R >> 2) & 3)) << 3)];
            #pragma unroll
            for (int wt = 0; wt < 2; ++wt) {
                int R2 = p * 32 + wt * 16 + lcol;
                short8v bz = *(const short8v*)&a2t[R2 * 32 + ((grp ^ ((R2 >> 1) & 3)) << 3)];
                float4v zc = {0.f, 0.f, 0.f, 0.f};
                zc = __builtin_amdgcn_mfma_f32_16x16x32_bf16(az, bz, zc, 0, 0, 0);
                int R3 = l_z * 32 + wt * 16 + lcol;
                int eb = (mt_z * 2 + (grp >> 1)) ^ ((R3 >> 1) & 3);
                unsigned* dst = (unsigned*)&Zb[R3 * 32 + (eb << 3) + ((grp & 1) << 2)];
                dst[0] = pk2(zc[0], zc[1]);
                dst[1] = pk2(zc[2], zc[3]);
            }
        }

        if (kc < NKC - 1) stage_w((kc + 1) & 1, kc + 1);

        asm volatile("s_waitcnt lgkmcnt(0)" ::: "memory");
        __builtin_amdgcn_sched_barrier(0);
        if (kc < NKC - 1) { asm volatile("s_waitcnt vmcnt(2)" ::: "memory"); }
        else              { asm volatile("s_waitcnt vmcnt(0)" ::: "memory"); }
        __builtin_amdgcn_sched_barrier(0);
        __builtin_amdgcn_s_barrier();

        // ---- main GEMM step ----
        {
            const __hip_bfloat16* wcur = &Wb[kc & 1][0];
            short8v af[4], bf[4];
            #pragma unroll
            for (int mt = 0; mt < 4; ++mt) {
                int c = wm * 64 + mt * 16 + lcol;
                af[mt] = *(const short8v*)&wcur[c * 32 + ((grp ^ ((c >> 1) & 3)) << 3)];
            }
            #pragma unroll
            for (int nt = 0; nt < 4; ++nt) {
                int R3 = wn * 64 + nt * 16 + lcol;
                bf[nt] = *(const short8v*)&Zb[R3 * 32 + ((grp ^ ((R3 >> 1) & 3)) << 3)];
            }
            __builtin_amdgcn_s_setprio(1);
            #pragma unroll
            for (int mt = 0; mt < 4; ++mt)
                #pragma unroll
                for (int nt = 0; nt < 4; ++nt)
                    acc[mt][nt] = __builtin_amdgcn_mfma_f32_16x16x32_bf16(af[mt], bf[nt], acc[mt][nt], 0, 0, 0);
            __builtin_amdgcn_s_setprio(0);
        }
        __builtin_amdgcn_s_barrier();
    }

    // ---- epilogue: BN + relu + residual + relu + store ----
    #pragma unroll
    for (int mt = 0; mt < 4; ++mt) {
        #pragma unroll
        for (int nt = 0; nt < 4; ++nt) {
            int w = ((wn * 64 + nt * 16) & 31) + 0;   // tile w-base (0 or 16)
            int l = l0 + ((wn * 64 + nt * 16) >> 5);
            int wl = w + lcol;
            if (wl < VV) {
                #pragma unroll
                for (int r = 0; r < 4; ++r) {
                    int c = wm * 64 + mt * 16 + grp * 4 + r;
                    float val = fmaf(acc[mt][nt][r], scsh[c], scsh[256 + c]);
                    val = fmaxf(val, 0.f);
                    size_t ad = ((size_t)(n * CC + c) * LL + l) * VV + wl;
                    val = fmaxf(val + x[ad], 0.f);
                    out[ad] = val;
                }
            }
        }
    }
}

// ===========================================================================
// Fallback path (ws too small): round-1/2 proven kernels (in-place on d_out)
// ===========================================================================
__global__ __launch_bounds__(256) void wsum_kernel(const float* __restrict__ x,
                                                   float* __restrict__ xs) {
    const int CHUNKS = 8;
    int t = blockIdx.x * 256 + threadIdx.x;
    if (t >= NB * CC * VV * CHUNKS) return;
    int v = t % VV;
    int r = t / VV;
    int chunk = r % CHUNKS;
    int nc = r / CHUNKS;
    int l0 = chunk * (LL / CHUNKS);
    const float* xp = x  + (size_t)nc * (LL * VV) + v;
    float*       op = xs + (size_t)nc * (LL * VV) + v;
    float ring[8];
    float run = 0.f;
    #pragma unroll
    for (int k = 0; k < 8; ++k) {
        int j = l0 - 8 + k;
        float val = (j >= 0) ? xp[j * VV] : 0.f;
        ring[k] = val; run += val;
    }
    for (int base = l0; base < l0 + LL / CHUNKS; base += 8) {
        #pragma unroll
        for (int k = 0; k < 8; ++k) {
            int l = base + k;
            float val = xp[l * VV];
            float o = run + val;
            op[l * VV] = o;
            run = o - ring[k];
            ring[k] = val;
        }
    }
}

__global__ __launch_bounds__(256) void fused_fallback_kernel(
    const float* xs, const float* __restrict__ x, const float* __restrict__ W,
    const float* __restrict__ A,
    const float* __restrict__ gamma, const float* __restrict__ beta,
    const float* __restrict__ mean, const float* __restrict__ var,
    float* out)
{
    __shared__ float xshf[CC][28];
    const int bid = blockIdx.x;
    const int n = bid >> 9;
    const int l = bid & 511;
    const int tid = threadIdx.x;
    const size_t nbase = (size_t)n * CC * LL * VV;
    for (int k = tid; k < CC * VV; k += 256) {
        int ci = k / VV, v = k - ci * VV;
        xshf[ci][v] = xs[nbase + (size_t)ci * (LL * VV) + (size_t)l * VV + v];
    }
    __syncthreads();
    const int c = tid;
    float Y[PP * VV];
    #pragma unroll
    for (int i = 0; i < PP * VV; ++i) Y[i] = 0.f;
    const float* Wpr = W + c * 256;
    #pragma unroll 1
    for (int ci = 0; ci < CC; ++ci) {
        float xv[VV];
        #pragma unroll
        for (int v = 0; v < VV; ++v) xv[v] = xshf[ci][v];
        float w0 = Wpr[ci], w1 = Wpr[65536 + ci], w2 = Wpr[131072 + ci];
        #pragma unroll
        for (int v = 0; v < VV; ++v) Y[v]          = fmaf(w0, xv[v], Y[v]);
        #pragma unroll
        for (int v = 0; v < VV; ++v) Y[VV + v]     = fmaf(w1, xv[v], Y[VV + v]);
        #pragma unroll
        for (int v = 0; v < VV; ++v) Y[2 * VV + v] = fmaf(w2, xv[v], Y[2 * VV + v]);
    }
    float o[VV];
    #pragma unroll
    for (int w = 0; w < VV; ++w) o[w] = 0.f;
    #pragma unroll
    for (int p = 0; p < PP; ++p)
        #pragma unroll
        for (int v = 0; v < VV; ++v) {
            float y = Y[p * VV + v];
            const float* Ap = A + (p * VV + v) * VV;
            #pragma unroll
            for (int w = 0; w < VV; ++w) o[w] = fmaf(y, Ap[w], o[w]);
        }
    float sc = gamma[c] * rsqrtf(var[c] + 1e-5f);
    float sh = beta[c] - mean[c] * sc;
    const float* resp = x   + nbase + (size_t)c * (LL * VV) + (size_t)l * VV;
    float*       outp = out + nbase + (size_t)c * (LL * VV) + (size_t)l * VV;
    #pragma unroll
    for (int w = 0; w < VV; ++w) {
        float t2 = fmaf(o[w], sc, sh);
        t2 = fmaxf(t2, 0.f);
        t2 = fmaxf(t2 + resp[w], 0.f);
        outp[w] = t2;
    }
}

extern "C" void kernel_launch(void* const* d_in, const int* in_sizes, int n_in,
                              void* d_out, int out_size, void* d_ws, size_t ws_size,
                              hipStream_t stream) {
    const float* x  = (const float*)d_in[0];
    const float* W  = (const float*)d_in[1];
    const float* A  = (const float*)d_in[2];
    const float* gm = (const float*)d_in[3];
    const float* bt = (const float*)d_in[4];
    const float* mn = (const float*)d_in[5];
    const float* vr = (const float*)d_in[6];
    float* out = (float*)d_out;

    if (ws_size >= (size_t)(OO * CC * sizeof(__hip_bfloat16))) {
        __hip_bfloat16* Wp = (__hip_bfloat16*)d_ws;
        wperm_kernel<<<dim3((OO * CC + 255) / 256), dim3(256), 0, stream>>>(W, Wp);
        fused_main_kernel<<<dim3(NB * (LL / LT)), dim3(512), 0, stream>>>(
            x, Wp, A, gm, bt, mn, vr, out);
    } else {
        const int threadsA = NB * CC * VV * 8;
        wsum_kernel<<<dim3((threadsA + 255) / 256), dim3(256), 0, stream>>>(x, out);
        fused_fallback_kernel<<<dim3(NB * LL), dim3(256), 0, stream>>>(
            out, x, W, A, gm, bt, mn, vr, out);
    }
}

// Round 5
// 112.676 us; speedup vs baseline: 3.1213x; 1.1424x over previous
//
#include <hip/hip_runtime.h>
#include <hip/hip_bf16.h>

#define NB 8
#define CC 256
#define OO 768
#define LL 512
#define VV 25
#define PP 3
#define KM 768
#define NKC 24          // K-chunks of 32
#define LT 4            // l's per block

typedef __attribute__((ext_vector_type(8))) short short8v;
typedef __attribute__((ext_vector_type(4))) float float4v;
typedef __attribute__((ext_vector_type(4))) int int4v;

__device__ inline short bf16b(float a){ __hip_bfloat16 h = __float2bfloat16(a); return *(short*)&h; }
__device__ inline unsigned pk2(float a, float b){
    __hip_bfloat16 ha = __float2bfloat16(a), hb = __float2bfloat16(b);
    unsigned short ua = *(unsigned short*)&ha, ub = *(unsigned short*)&hb;
    return (unsigned)ua | ((unsigned)ub << 16);
}
__device__ inline void gload_lds16(const void* g, void* s) {
    __builtin_amdgcn_global_load_lds((const __attribute__((address_space(1))) unsigned*)g,
                                     (__attribute__((address_space(3))) unsigned*)(s), 16, 0, 0);
}

// ---------------------------------------------------------------------------
// W' permutation into d_ws (bf16): Wp[c][k] = W[(p*256+c)][ci]
// k-order: k = cib*192 + p*64 + ci6,  ci = cib*64 + ci6
// ---------------------------------------------------------------------------
__global__ __launch_bounds__(256) void wperm_kernel(const float* __restrict__ W,
                                                    __hip_bfloat16* __restrict__ Wp) {
    int idx = blockIdx.x * 256 + threadIdx.x;
    if (idx >= OO * CC) return;
    int c = idx / KM;
    int k = idx - c * KM;
    int cib = k / 192, r = k - cib * 192;
    int p = r >> 6, ci6 = r & 63;
    Wp[idx] = __float2bfloat16(W[(p * 256 + c) * 256 + cib * 64 + ci6]);
}

// ---------------------------------------------------------------------------
// Fused: window-sum + Z-gen(1-ahead, dbuf) + K=768 MFMA GEMM + BN/relu/res.
// Block = (n, 4 l's). 512 threads / 8 waves. 1 barrier per K-chunk.
// ---------------------------------------------------------------------------
__global__ __launch_bounds__(512, 4) void fused_main_kernel(
    const float* __restrict__ x,
    const __hip_bfloat16* __restrict__ Wp,
    const float* __restrict__ A,
    const float* __restrict__ gamma, const float* __restrict__ beta,
    const float* __restrict__ mean, const float* __restrict__ var,
    float* __restrict__ out)
{
    __shared__ __hip_bfloat16 Wb[2][256 * 32];   // W'-chunk dbuf (32 KB)
    __shared__ __hip_bfloat16 Zb[2][128 * 32];   // Z^T dbuf (16 KB)
    __shared__ __hip_bfloat16 xsh[256 * 32];     // ws-x [ci6*4+l][v pad32] (16 KB)
    __shared__ __hip_bfloat16 a2t[3 * 32 * 32];  // A^T [p*32+w][v pad32] (6 KB)
    __shared__ float scsh[512];

    const int tid  = threadIdx.x;
    const int lane = tid & 63, wid = tid >> 6;
    const int lcol = lane & 15, grp = lane >> 4;
    const int bid0 = blockIdx.x;
    const int swz = (bid0 & 7) * 128 + (bid0 >> 3);   // XCD-contiguous work chunks
    const int n  = swz >> 7;
    const int l0 = (swz & 127) * LT;
    const int wm = wid >> 1, wn = wid & 1;       // main-GEMM wave grid 4M x 2N
    const int l_z = wid >> 1, mt_z = wid & 1;    // zgen wave roles

    const int c_st  = tid >> 2;                  // 0..127
    const int kb_st = (tid & 3) ^ ((c_st >> 1) & 3);

    // ---- prologue: zero pads, BN coefs ----
    {
        int4v z = {0, 0, 0, 0};
        ((int4v*)xsh)[tid] = z;
        ((int4v*)xsh)[tid + 512] = z;
        if (tid < 384) ((int4v*)a2t)[tid] = z;
        int c = tid & 255;
        float sc = gamma[c] * rsqrtf(var[c] + 1e-5f);
        if (tid < 256) scsh[tid] = sc;
        else           scsh[tid] = beta[c] - mean[c] * sc;
    }
    __syncthreads();
    // A^T scatter: a2t[p*32 + w][v ^ swz]
    for (int idx = tid; idx < PP * VV * VV; idx += 512) {
        int p = idx / 625, r = idx - p * 625, v = r / 25, w = r - v * 25;
        int R = p * 32 + w;
        int e = (((v >> 3) ^ ((R >> 1) & 3)) << 3) | (v & 7);
        a2t[R * 32 + e] = __float2bfloat16(A[idx]);
    }

    auto stage_w = [&](int buf, int kc_) {
        #pragma unroll
        for (int it = 0; it < 2; ++it) {
            const __hip_bfloat16* s = Wp + (size_t)(c_st + it * 128) * KM + kc_ * 32 + kb_st * 8;
            gload_lds16((const void*)s, (void*)((char*)&Wb[buf][0] + it * 8192 + wid * 1024));
        }
    };
    auto stage_xs = [&](int cib) {
        for (int cc = tid; cc < 1600; cc += 512) {
            int ci6 = cc / 25, v = cc - ci6 * 25;
            const float* xp = x + ((size_t)(n * CC + cib * 64 + ci6) * LL) * VV + v;
            float rbuf[12];
            #pragma unroll
            for (int j = 0; j < 12; ++j) {
                int lj = l0 - 8 + j;
                rbuf[j] = (lj >= 0) ? xp[(size_t)lj * VV] : 0.f;
            }
            float wsv = 0.f;
            #pragma unroll
            for (int j = 0; j < 9; ++j) wsv += rbuf[j];
            #pragma unroll
            for (int i = 0; i < 4; ++i) {
                int R = ci6 * 4 + i;
                int e = (((v >> 3) ^ ((R >> 2) & 3)) << 3) | (v & 7);
                xsh[R * 32 + e] = __float2bfloat16(wsv);
                if (i < 3) wsv += rbuf[9 + i] - rbuf[i];
            }
        }
    };
    auto zgen = [&](int kc, int zbuf) {
        int p = (kc % 6) >> 1, h = kc & 1;
        int ci6 = h * 32 + mt_z * 16 + lcol;
        int R = ci6 * 4 + l_z;
        short8v az = *(const short8v*)&xsh[R * 32 + ((grp ^ ((R >> 2) & 3)) << 3)];
        #pragma unroll
        for (int wt = 0; wt < 2; ++wt) {
            int R2 = p * 32 + wt * 16 + lcol;
            short8v bz = *(const short8v*)&a2t[R2 * 32 + ((grp ^ ((R2 >> 1) & 3)) << 3)];
            float4v zc = {0.f, 0.f, 0.f, 0.f};
            zc = __builtin_amdgcn_mfma_f32_16x16x32_bf16(az, bz, zc, 0, 0, 0);
            int R3 = l_z * 32 + wt * 16 + lcol;
            int eb = (mt_z * 2 + (grp >> 1)) ^ ((R3 >> 1) & 3);
            unsigned* dst = (unsigned*)&Zb[zbuf][R3 * 32 + (eb << 3) + ((grp & 1) << 2)];
            dst[0] = pk2(zc[0], zc[1]);
            dst[1] = pk2(zc[2], zc[3]);
        }
    };

    float4v acc[4][4];
    #pragma unroll
    for (int i = 0; i < 4; ++i)
        #pragma unroll
        for (int j = 0; j < 4; ++j) acc[i][j] = (float4v){0.f, 0.f, 0.f, 0.f};

    stage_w(0, 0);   // prime W chunk 0

    #pragma unroll 1
    for (int cib = 0; cib < 4; ++cib) {
        stage_xs(cib);
        asm volatile("s_waitcnt lgkmcnt(0)" ::: "memory");
        __builtin_amdgcn_sched_barrier(0);
        __builtin_amdgcn_s_barrier();
        __builtin_amdgcn_sched_barrier(0);

        zgen(cib * 6, (cib * 6) & 1);                   // prime Z for first chunk
        asm volatile("s_waitcnt lgkmcnt(0) vmcnt(0)" ::: "memory");
        __builtin_amdgcn_sched_barrier(0);
        __builtin_amdgcn_s_barrier();
        __builtin_amdgcn_sched_barrier(0);

        #pragma unroll 1
        for (int j = 0; j < 6; ++j) {
            const int kc = cib * 6 + j;
            if (kc + 1 < NKC) stage_w((kc + 1) & 1, kc + 1);

            if (j < 5) zgen(kc + 1, (kc + 1) & 1);      // Z one chunk ahead

            const __hip_bfloat16* wcur = &Wb[kc & 1][0];
            const __hip_bfloat16* zcur = &Zb[kc & 1][0];
            short8v af[4], bf[4];
            #pragma unroll
            for (int mt = 0; mt < 4; ++mt) {
                int c = wm * 64 + mt * 16 + lcol;
                af[mt] = *(const short8v*)&wcur[c * 32 + ((grp ^ ((c >> 1) & 3)) << 3)];
            }
            #pragma unroll
            for (int nt = 0; nt < 4; ++nt) {
                int R3 = wn * 64 + nt * 16 + lcol;
                bf[nt] = *(const short8v*)&zcur[R3 * 32 + ((grp ^ ((R3 >> 1) & 3)) << 3)];
            }

            __builtin_amdgcn_s_setprio(1);
            #pragma unroll
            for (int mt = 0; mt < 4; ++mt)
                #pragma unroll
                for (int nt = 0; nt < 4; ++nt)
                    acc[mt][nt] = __builtin_amdgcn_mfma_f32_16x16x32_bf16(af[mt], bf[nt], acc[mt][nt], 0, 0, 0);
            __builtin_amdgcn_s_setprio(0);

            asm volatile("s_waitcnt lgkmcnt(0)" ::: "memory");
            __builtin_amdgcn_sched_barrier(0);
            if (kc + 1 < NKC) { asm volatile("s_waitcnt vmcnt(2)" ::: "memory"); }
            else              { asm volatile("s_waitcnt vmcnt(0)" ::: "memory"); }
            __builtin_amdgcn_sched_barrier(0);
            __builtin_amdgcn_s_barrier();
            __builtin_amdgcn_sched_barrier(0);
        }
    }

    // ---- epilogue: BN + relu + residual + relu + store ----
    #pragma unroll
    for (int mt = 0; mt < 4; ++mt) {
        #pragma unroll
        for (int nt = 0; nt < 4; ++nt) {
            int w = (wn * 64 + nt * 16) & 31;
            int l = l0 + ((wn * 64 + nt * 16) >> 5);
            int wl = w + lcol;
            if (wl < VV) {
                #pragma unroll
                for (int r = 0; r < 4; ++r) {
                    int c = wm * 64 + mt * 16 + grp * 4 + r;
                    float val = fmaf(acc[mt][nt][r], scsh[c], scsh[256 + c]);
                    val = fmaxf(val, 0.f);
                    size_t ad = ((size_t)(n * CC + c) * LL + l) * VV + wl;
                    val = fmaxf(val + x[ad], 0.f);
                    out[ad] = val;
                }
            }
        }
    }
}

// ===========================================================================
// Fallback path (ws too small): round-1/2 proven kernels (in-place on d_out)
// ===========================================================================
__global__ __launch_bounds__(256) void wsum_kernel(const float* __restrict__ x,
                                                   float* __restrict__ xs) {
    const int CHUNKS = 8;
    int t = blockIdx.x * 256 + threadIdx.x;
    if (t >= NB * CC * VV * CHUNKS) return;
    int v = t % VV;
    int r = t / VV;
    int chunk = r % CHUNKS;
    int nc = r / CHUNKS;
    int l0 = chunk * (LL / CHUNKS);
    const float* xp = x  + (size_t)nc * (LL * VV) + v;
    float*       op = xs + (size_t)nc * (LL * VV) + v;
    float ring[8];
    float run = 0.f;
    #pragma unroll
    for (int k = 0; k < 8; ++k) {
        int j = l0 - 8 + k;
        float val = (j >= 0) ? xp[j * VV] : 0.f;
        ring[k] = val; run += val;
    }
    for (int base = l0; base < l0 + LL / CHUNKS; base += 8) {
        #pragma unroll
        for (int k = 0; k < 8; ++k) {
            int l = base + k;
            float val = xp[l * VV];
            float o = run + val;
            op[l * VV] = o;
            run = o - ring[k];
            ring[k] = val;
        }
    }
}

__global__ __launch_bounds__(256) void fused_fallback_kernel(
    const float* xs, const float* __restrict__ x, const float* __restrict__ W,
    const float* __restrict__ A,
    const float* __restrict__ gamma, const float* __restrict__ beta,
    const float* __restrict__ mean, const float* __restrict__ var,
    float* out)
{
    __shared__ float xshf[CC][28];
    const int bid = blockIdx.x;
    const int n = bid >> 9;
    const int l = bid & 511;
    const int tid = threadIdx.x;
    const size_t nbase = (size_t)n * CC * LL * VV;
    for (int k = tid; k < CC * VV; k += 256) {
        int ci = k / VV, v = k - ci * VV;
        xshf[ci][v] = xs[nbase + (size_t)ci * (LL * VV) + (size_t)l * VV + v];
    }
    __syncthreads();
    const int c = tid;
    float Y[PP * VV];
    #pragma unroll
    for (int i = 0; i < PP * VV; ++i) Y[i] = 0.f;
    const float* Wpr = W + c * 256;
    #pragma unroll 1
    for (int ci = 0; ci < CC; ++ci) {
        float xv[VV];
        #pragma unroll
        for (int v = 0; v < VV; ++v) xv[v] = xshf[ci][v];
        float w0 = Wpr[ci], w1 = Wpr[65536 + ci], w2 = Wpr[131072 + ci];
        #pragma unroll
        for (int v = 0; v < VV; ++v) Y[v]          = fmaf(w0, xv[v], Y[v]);
        #pragma unroll
        for (int v = 0; v < VV; ++v) Y[VV + v]     = fmaf(w1, xv[v], Y[VV + v]);
        #pragma unroll
        for (int v = 0; v < VV; ++v) Y[2 * VV + v] = fmaf(w2, xv[v], Y[2 * VV + v]);
    }
    float o[VV];
    #pragma unroll
    for (int w = 0; w < VV; ++w) o[w] = 0.f;
    #pragma unroll
    for (int p = 0; p < PP; ++p)
        #pragma unroll
        for (int v = 0; v < VV; ++v) {
            float y = Y[p * VV + v];
            const float* Ap = A + (p * VV + v) * VV;
            #pragma unroll
            for (int w = 0; w < VV; ++w) o[w] = fmaf(y, Ap[w], o[w]);
        }
    float sc = gamma[c] * rsqrtf(var[c] + 1e-5f);
    float sh = beta[c] - mean[c] * sc;
    const float* resp = x   + nbase + (size_t)c * (LL * VV) + (size_t)l * VV;
    float*       outp = out + nbase + (size_t)c * (LL * VV) + (size_t)l * VV;
    #pragma unroll
    for (int w = 0; w < VV; ++w) {
        float t2 = fmaf(o[w], sc, sh);
        t2 = fmaxf(t2, 0.f);
        t2 = fmaxf(t2 + resp[w], 0.f);
        outp[w] = t2;
    }
}

extern "C" void kernel_launch(void* const* d_in, const int* in_sizes, int n_in,
                              void* d_out, int out_size, void* d_ws, size_t ws_size,
                              hipStream_t stream) {
    const float* x  = (const float*)d_in[0];
    const float* W  = (const float*)d_in[1];
    const float* A  = (const float*)d_in[2];
    const float* gm = (const float*)d_in[3];
    const float* bt = (const float*)d_in[4];
    const float* mn = (const float*)d_in[5];
    const float* vr = (const float*)d_in[6];
    float* out = (float*)d_out;

    if (ws_size >= (size_t)(OO * CC * sizeof(__hip_bfloat16))) {
        __hip_bfloat16* Wp = (__hip_bfloat16*)d_ws;
        wperm_kernel<<<dim3((OO * CC + 255) / 256), dim3(256), 0, stream>>>(W, Wp);
        fused_main_kernel<<<dim3(NB * (LL / LT)), dim3(512), 0, stream>>>(
            x, Wp, A, gm, bt, mn, vr, out);
    } else {
        const int threadsA = NB * CC * VV * 8;
        wsum_kernel<<<dim3((threadsA + 255) / 256), dim3(256), 0, stream>>>(x, out);
        fused_fallback_kernel<<<dim3(NB * LL), dim3(256), 0, stream>>>(
            out, x, W, A, gm, bt, mn, vr, out);
    }
}

// Round 6
// 107.346 us; speedup vs baseline: 3.2763x; 1.0497x over previous
//
#include <hip/hip_runtime.h>
#include <hip/hip_bf16.h>

#define NB 8
#define CC 256
#define OO 768
#define LL 512
#define VV 25
#define PP 3
#define KM 768
#define NKC 24          // K-chunks of 32
#define LT 4            // l's per block

typedef __attribute__((ext_vector_type(8))) short short8v;
typedef __attribute__((ext_vector_type(4))) float float4v;
typedef __attribute__((ext_vector_type(4))) int int4v;

__device__ inline unsigned pk2(float a, float b){
    __hip_bfloat16 ha = __float2bfloat16(a), hb = __float2bfloat16(b);
    unsigned short ua = *(unsigned short*)&ha, ub = *(unsigned short*)&hb;
    return (unsigned)ua | ((unsigned)ub << 16);
}

// ---------------------------------------------------------------------------
// W -> fragment-ordered bf16 layout in d_ws:
//   Wp2[idx], idx = (((kc*4 + wm)*4 + mt)*64 + lane)*8 + j
//   holds W'[c][k] with c = wm*64+mt*16+(lane&15), k = kc*32+(lane>>4)*8+j
//   and W'[c][k] = W[(p*256+c)*256 + ci], k = cib*192+p*64+ci6, ci=cib*64+ci6.
// Each wave's af fragment load becomes one coalesced 16B/lane global load.
// ---------------------------------------------------------------------------
__global__ __launch_bounds__(256) void wperm_kernel(const float* __restrict__ W,
                                                    __hip_bfloat16* __restrict__ Wp) {
    int idx = blockIdx.x * 256 + threadIdx.x;
    if (idx >= OO * CC) return;
    int j    = idx & 7;
    int lane = (idx >> 3) & 63;
    int mt   = (idx >> 9) & 3;
    int wm   = (idx >> 11) & 3;
    int kc   = idx >> 13;                    // 0..23
    int c = wm * 64 + mt * 16 + (lane & 15);
    int k = kc * 32 + ((lane >> 4) << 3) + j;
    int cib = k / 192;
    int r = k - cib * 192;
    int p = r >> 6;
    int ci = cib * 64 + (r & 63);
    Wp[idx] = __float2bfloat16(W[(p * 256 + c) * 256 + ci]);
}

// ---------------------------------------------------------------------------
// Fused: window-sum + Z-gen(1-ahead, dbuf) + K=768 MFMA GEMM + BN/relu/res.
// Block = (n, 4 l's). 512 threads / 8 waves. W-fragments direct from global
// (L2-resident), Z double-buffered in LDS, 1 barrier per K-chunk.
// ---------------------------------------------------------------------------
__global__ __launch_bounds__(512, 4) void fused_main_kernel(
    const float* __restrict__ x,
    const __hip_bfloat16* __restrict__ Wp,
    const float* __restrict__ A,
    const float* __restrict__ gamma, const float* __restrict__ beta,
    const float* __restrict__ mean, const float* __restrict__ var,
    float* __restrict__ out)
{
    __shared__ __hip_bfloat16 Zb[2][128 * 32];   // Z^T dbuf (16 KB)
    __shared__ __hip_bfloat16 xsh[256 * 32];     // ws-x [ci6*4+l][v pad32] (16 KB)
    __shared__ __hip_bfloat16 a2t[3 * 32 * 32];  // A^T [p*32+w][v pad32] (6 KB)
    __shared__ float scsh[512];

    const int tid  = threadIdx.x;
    const int lane = tid & 63, wid = tid >> 6;
    const int lcol = lane & 15, grp = lane >> 4;
    const int bid0 = blockIdx.x;
    const int swz = (bid0 & 7) * 128 + (bid0 >> 3);   // XCD-contiguous chunks
    const int n  = swz >> 7;
    const int l0 = (swz & 127) * LT;
    const int wm = wid >> 1, wn = wid & 1;       // main-GEMM wave grid 4M x 2N
    const int l_z = wid >> 1, mt_z = wid & 1;    // zgen wave roles

    // ---- prologue: zero pads, BN coefs ----
    {
        int4v z = {0, 0, 0, 0};
        ((int4v*)xsh)[tid] = z;
        ((int4v*)xsh)[tid + 512] = z;
        if (tid < 384) ((int4v*)a2t)[tid] = z;
        int c = tid & 255;
        float sc = gamma[c] * rsqrtf(var[c] + 1e-5f);
        if (tid < 256) scsh[tid] = sc;
        else           scsh[tid] = beta[c] - mean[c] * sc;
    }
    __syncthreads();
    // A^T scatter: a2t[p*32 + w][v ^ swz]
    for (int idx = tid; idx < PP * VV * VV; idx += 512) {
        int p = idx / 625, r = idx - p * 625, v = r / 25, w = r - v * 25;
        int R = p * 32 + w;
        int e = (((v >> 3) ^ ((R >> 1) & 3)) << 3) | (v & 7);
        a2t[R * 32 + e] = __float2bfloat16(A[idx]);
    }

    auto stage_xs = [&](int cib) {
        for (int cc = tid; cc < 1600; cc += 512) {
            int ci6 = cc / 25, v = cc - ci6 * 25;
            const float* xp = x + ((size_t)(n * CC + cib * 64 + ci6) * LL) * VV + v;
            float rbuf[12];
            #pragma unroll
            for (int j = 0; j < 12; ++j) {
                int lj = l0 - 8 + j;
                rbuf[j] = (lj >= 0) ? xp[(size_t)lj * VV] : 0.f;
            }
            float wsv = 0.f;
            #pragma unroll
            for (int j = 0; j < 9; ++j) wsv += rbuf[j];
            #pragma unroll
            for (int i = 0; i < 4; ++i) {
                int R = ci6 * 4 + i;
                int e = (((v >> 3) ^ ((R >> 2) & 3)) << 3) | (v & 7);
                xsh[R * 32 + e] = __float2bfloat16(wsv);
                if (i < 3) wsv += rbuf[9 + i] - rbuf[i];
            }
        }
    };
    auto zgen = [&](int kc, int zbuf) {
        int p = (kc % 6) >> 1, h = kc & 1;
        int ci6 = h * 32 + mt_z * 16 + lcol;
        int R = ci6 * 4 + l_z;
        short8v az = *(const short8v*)&xsh[R * 32 + ((grp ^ ((R >> 2) & 3)) << 3)];
        #pragma unroll
        for (int wt = 0; wt < 2; ++wt) {
            int R2 = p * 32 + wt * 16 + lcol;
            short8v bz = *(const short8v*)&a2t[R2 * 32 + ((grp ^ ((R2 >> 1) & 3)) << 3)];
            float4v zc = {0.f, 0.f, 0.f, 0.f};
            zc = __builtin_amdgcn_mfma_f32_16x16x32_bf16(az, bz, zc, 0, 0, 0);
            int R3 = l_z * 32 + wt * 16 + lcol;
            int eb = (mt_z * 2 + (grp >> 1)) ^ ((R3 >> 1) & 3);
            unsigned* dst = (unsigned*)&Zb[zbuf][R3 * 32 + (eb << 3) + ((grp & 1) << 2)];
            dst[0] = pk2(zc[0], zc[1]);
            dst[1] = pk2(zc[2], zc[3]);
        }
    };

    float4v acc[4][4];
    #pragma unroll
    for (int i = 0; i < 4; ++i)
        #pragma unroll
        for (int j = 0; j < 4; ++j) acc[i][j] = (float4v){0.f, 0.f, 0.f, 0.f};

    // per-thread af base: fragment groups of 512 elems per (wm,mt), 8192 per kc
    const __hip_bfloat16* afbase = Wp + ((size_t)(wm * 4) * 64 + lane) * 8;

    #pragma unroll 1
    for (int cib = 0; cib < 4; ++cib) {
        stage_xs(cib);
        asm volatile("s_waitcnt lgkmcnt(0)" ::: "memory");
        __builtin_amdgcn_sched_barrier(0);
        __builtin_amdgcn_s_barrier();
        __builtin_amdgcn_sched_barrier(0);

        zgen(cib * 6, (cib * 6) & 1);                   // prime Z for first chunk
        asm volatile("s_waitcnt lgkmcnt(0)" ::: "memory");
        __builtin_amdgcn_sched_barrier(0);
        __builtin_amdgcn_s_barrier();
        __builtin_amdgcn_sched_barrier(0);

        #pragma unroll 1
        for (int j = 0; j < 6; ++j) {
            const int kc = cib * 6 + j;

            // A-fragments direct from global (L2-resident, coalesced 16B/lane)
            short8v af[4];
            {
                const __hip_bfloat16* ap = afbase + kc * 8192;
                #pragma unroll
                for (int mt = 0; mt < 4; ++mt)
                    af[mt] = *(const short8v*)(ap + mt * 512);
            }

            if (j < 5) zgen(kc + 1, (kc + 1) & 1);      // Z one chunk ahead

            const __hip_bfloat16* zcur = &Zb[kc & 1][0];
            short8v bf[4];
            #pragma unroll
            for (int nt = 0; nt < 4; ++nt) {
                int R3 = wn * 64 + nt * 16 + lcol;
                bf[nt] = *(const short8v*)&zcur[R3 * 32 + ((grp ^ ((R3 >> 1) & 3)) << 3)];
            }

            __builtin_amdgcn_s_setprio(1);
            #pragma unroll
            for (int mt = 0; mt < 4; ++mt)
                #pragma unroll
                for (int nt = 0; nt < 4; ++nt)
                    acc[mt][nt] = __builtin_amdgcn_mfma_f32_16x16x32_bf16(af[mt], bf[nt], acc[mt][nt], 0, 0, 0);
            __builtin_amdgcn_s_setprio(0);

            asm volatile("s_waitcnt lgkmcnt(0)" ::: "memory");
            __builtin_amdgcn_sched_barrier(0);
            __builtin_amdgcn_s_barrier();
            __builtin_amdgcn_sched_barrier(0);
        }
    }

    // ---- epilogue: BN + relu + residual + relu + store ----
    #pragma unroll
    for (int mt = 0; mt < 4; ++mt) {
        #pragma unroll
        for (int nt = 0; nt < 4; ++nt) {
            int w = (wn * 64 + nt * 16) & 31;
            int l = l0 + ((wn * 64 + nt * 16) >> 5);
            int wl = w + lcol;
            if (wl < VV) {
                #pragma unroll
                for (int r = 0; r < 4; ++r) {
                    int c = wm * 64 + mt * 16 + grp * 4 + r;
                    float val = fmaf(acc[mt][nt][r], scsh[c], scsh[256 + c]);
                    val = fmaxf(val, 0.f);
                    size_t ad = ((size_t)(n * CC + c) * LL + l) * VV + wl;
                    val = fmaxf(val + x[ad], 0.f);
                    out[ad] = val;
                }
            }
        }
    }
}

// ===========================================================================
// Fallback path (ws too small): round-1/2 proven kernels (in-place on d_out)
// ===========================================================================
__global__ __launch_bounds__(256) void wsum_kernel(const float* __restrict__ x,
                                                   float* __restrict__ xs) {
    const int CHUNKS = 8;
    int t = blockIdx.x * 256 + threadIdx.x;
    if (t >= NB * CC * VV * CHUNKS) return;
    int v = t % VV;
    int r = t / VV;
    int chunk = r % CHUNKS;
    int nc = r / CHUNKS;
    int l0 = chunk * (LL / CHUNKS);
    const float* xp = x  + (size_t)nc * (LL * VV) + v;
    float*       op = xs + (size_t)nc * (LL * VV) + v;
    float ring[8];
    float run = 0.f;
    #pragma unroll
    for (int k = 0; k < 8; ++k) {
        int j = l0 - 8 + k;
        float val = (j >= 0) ? xp[j * VV] : 0.f;
        ring[k] = val; run += val;
    }
    for (int base = l0; base < l0 + LL / CHUNKS; base += 8) {
        #pragma unroll
        for (int k = 0; k < 8; ++k) {
            int l = base + k;
            float val = xp[l * VV];
            float o = run + val;
            op[l * VV] = o;
            run = o - ring[k];
            ring[k] = val;
        }
    }
}

__global__ __launch_bounds__(256) void fused_fallback_kernel(
    const float* xs, const float* __restrict__ x, const float* __restrict__ W,
    const float* __restrict__ A,
    const float* __restrict__ gamma, const float* __restrict__ beta,
    const float* __restrict__ mean, const float* __restrict__ var,
    float* out)
{
    __shared__ float xshf[CC][28];
    const int bid = blockIdx.x;
    const int n = bid >> 9;
    const int l = bid & 511;
    const int tid = threadIdx.x;
    const size_t nbase = (size_t)n * CC * LL * VV;
    for (int k = tid; k < CC * VV; k += 256) {
        int ci = k / VV, v = k - ci * VV;
        xshf[ci][v] = xs[nbase + (size_t)ci * (LL * VV) + (size_t)l * VV + v];
    }
    __syncthreads();
    const int c = tid;
    float Y[PP * VV];
    #pragma unroll
    for (int i = 0; i < PP * VV; ++i) Y[i] = 0.f;
    const float* Wpr = W + c * 256;
    #pragma unroll 1
    for (int ci = 0; ci < CC; ++ci) {
        float xv[VV];
        #pragma unroll
        for (int v = 0; v < VV; ++v) xv[v] = xshf[ci][v];
        float w0 = Wpr[ci], w1 = Wpr[65536 + ci], w2 = Wpr[131072 + ci];
        #pragma unroll
        for (int v = 0; v < VV; ++v) Y[v]          = fmaf(w0, xv[v], Y[v]);
        #pragma unroll
        for (int v = 0; v < VV; ++v) Y[VV + v]     = fmaf(w1, xv[v], Y[VV + v]);
        #pragma unroll
        for (int v = 0; v < VV; ++v) Y[2 * VV + v] = fmaf(w2, xv[v], Y[2 * VV + v]);
    }
    float o[VV];
    #pragma unroll
    for (int w = 0; w < VV; ++w) o[w] = 0.f;
    #pragma unroll
    for (int p = 0; p < PP; ++p)
        #pragma unroll
        for (int v = 0; v < VV; ++v) {
            float y = Y[p * VV + v];
            const float* Ap = A + (p * VV + v) * VV;
            #pragma unroll
            for (int w = 0; w < VV; ++w) o[w] = fmaf(y, Ap[w], o[w]);
        }
    float sc = gamma[c] * rsqrtf(var[c] + 1e-5f);
    float sh = beta[c] - mean[c] * sc;
    const float* resp = x   + nbase + (size_t)c * (LL * VV) + (size_t)l * VV;
    float*       outp = out + nbase + (size_t)c * (LL * VV) + (size_t)l * VV;
    #pragma unroll
    for (int w = 0; w < VV; ++w) {
        float t2 = fmaf(o[w], sc, sh);
        t2 = fmaxf(t2, 0.f);
        t2 = fmaxf(t2 + resp[w], 0.f);
        outp[w] = t2;
    }
}

extern "C" void kernel_launch(void* const* d_in, const int* in_sizes, int n_in,
                              void* d_out, int out_size, void* d_ws, size_t ws_size,
                              hipStream_t stream) {
    const float* x  = (const float*)d_in[0];
    const float* W  = (const float*)d_in[1];
    const float* A  = (const float*)d_in[2];
    const float* gm = (const float*)d_in[3];
    const float* bt = (const float*)d_in[4];
    const float* mn = (const float*)d_in[5];
    const float* vr = (const float*)d_in[6];
    float* out = (float*)d_out;

    if (ws_size >= (size_t)(OO * CC * sizeof(__hip_bfloat16))) {
        __hip_bfloat16* Wp = (__hip_bfloat16*)d_ws;
        wperm_kernel<<<dim3((OO * CC + 255) / 256), dim3(256), 0, stream>>>(W, Wp);
        fused_main_kernel<<<dim3(NB * (LL / LT)), dim3(512), 0, stream>>>(
            x, Wp, A, gm, bt, mn, vr, out);
    } else {
        const int threadsA = NB * CC * VV * 8;
        wsum_kernel<<<dim3((threadsA + 255) / 256), dim3(256), 0, stream>>>(x, out);
        fused_fallback_kernel<<<dim3(NB * LL), dim3(256), 0, stream>>>(
            out, x, W, A, gm, bt, mn, vr, out);
    }
}